// Round 1
// baseline (122940.784 us; speedup 1.0000x reference)
//
#include <hip/hip_runtime.h>

#define TT 512

typedef _Float16 f16;
typedef _Float16 half8 __attribute__((ext_vector_type(8)));
typedef float f32x4 __attribute__((ext_vector_type(4)));

#define MFMA(a,b,c) __builtin_amdgcn_mfma_f32_16x16x32_f16((a),(b),(c),0,0,0)
#define LOSC  2048.0f
#define RLOSC 0.00048828125f   // 1/2048

// LDS partial layout: per-wave region of 16 rows, row stride 18 floats.
// Row stride 18 => q-group stride 4*18=72 = 8 (mod 32) banks -> the f32x4
// partial store is 2-way (free) instead of 4-way conflicted.
#define RS  18
#define WSZ (16*RS)      // 288 floats per wave region
#define LSZ (16*WSZ)     // 4608 floats per buffer (18.4 KB)

__device__ __forceinline__ half8 ldh8(const f16* p){ return *(const half8*)p; }
__device__ __forceinline__ float sgm(float x){ return 1.f/(1.f+__expf(-x)); }
// act kinds: 0 tanh, 1 sigmoid, 2 relu, 3 identity
__device__ __forceinline__ float applyact(int k, float x){
  if (k==0) return tanhf(x);
  if (k==1) return sgm(x);
  if (k==2) return fmaxf(x,0.f);
  return x;
}

// ---- grid barrier for 64 blocks: 8 lines x 8 blocks, monotonic counters ----
__device__ __forceinline__ void gbar(unsigned* bar, unsigned ph){
  __syncthreads();
  if (threadIdx.x==0){
    __builtin_amdgcn_fence(__ATOMIC_RELEASE, "agent");
    unsigned g = blockIdx.x & 7u;
    unsigned t = __hip_atomic_fetch_add(&bar[g*32], 1u, __ATOMIC_ACQ_REL, __HIP_MEMORY_SCOPE_AGENT);
    if (t == ph*8u + 7u){
      unsigned d = __hip_atomic_fetch_add(&bar[512], 1u, __ATOMIC_ACQ_REL, __HIP_MEMORY_SCOPE_AGENT);
      if (d == ph*8u + 7u)
        __hip_atomic_store(&bar[544], ph+1u, __ATOMIC_RELEASE, __HIP_MEMORY_SCOPE_AGENT);
    }
    while (__hip_atomic_load(&bar[544], __ATOMIC_RELAXED, __HIP_MEMORY_SCOPE_AGENT) <= ph)
      __builtin_amdgcn_s_sleep(1);
    __builtin_amdgcn_fence(__ATOMIC_ACQUIRE, "agent");
  }
  __syncthreads();
}

// ---- one node matmul, K=1024. Block computes out rows 0..63, cols c0..c0+15.
// waves: wid = ks*4 + mtile; mtile = 16-row tile, ks = K-slice of 256.
// Register-shared fragments: Ah used 3x, Wh used 2x -> 6 loads / 6 MFMAs.
__device__ __forceinline__ void node_mm(
  const f16* __restrict__ AH, const f16* __restrict__ AL,
  const f16* __restrict__ Wh, const f16* __restrict__ Wl,
  float* __restrict__ Lg, float* __restrict__ La,
  int wid, int q8, int l15, int c0, int wlo)
{
  const int mtile = wid & 3, ks = wid >> 2;
  const int m0 = mtile*16, k0 = ks*256;
  const f16* Ap  = AH + (m0+l15)*1024 + k0 + q8;
  const f16* Alp = AL + (m0+l15)*1024 + k0 + q8;
  const f16* Bg  = Wh + (c0+l15)*1024 + k0 + q8;
  const f16* Ba  = Wh + (1024+c0+l15)*1024 + k0 + q8;
  f32x4 g0={0,0,0,0},g1={0,0,0,0},a0={0,0,0,0},a1={0,0,0,0};
  if (wlo){
    const f16* Bgl = Wl + (c0+l15)*1024 + k0 + q8;
    const f16* Bal = Wl + (1024+c0+l15)*1024 + k0 + q8;
    #pragma unroll 2
    for (int s=0;s<256;s+=32){
      half8 ah=ldh8(Ap+s), al=ldh8(Alp+s);
      half8 wg=ldh8(Bg+s), wa=ldh8(Ba+s);
      g0=MFMA(ah,wg,g0); a0=MFMA(ah,wa,a0);
      g1=MFMA(al,wg,g1); a1=MFMA(al,wa,a1);
      g1=MFMA(ah,ldh8(Bgl+s),g1); a1=MFMA(ah,ldh8(Bal+s),a1);
    }
  } else {
    #pragma unroll 2
    for (int s=0;s<256;s+=32){
      half8 ah=ldh8(Ap+s), al=ldh8(Alp+s);
      half8 wg=ldh8(Bg+s), wa=ldh8(Ba+s);
      g0=MFMA(ah,wg,g0); a0=MFMA(ah,wa,a0);
      g1=MFMA(al,wg,g1); a1=MFMA(al,wa,a1);
    }
  }
  f32x4 gg = g0 + g1*RLOSC, aa = a0 + a1*RLOSC;
  const int base = wid*WSZ + (q8>>1)*RS + l15;   // row-in-tile = q*4+rr
  #pragma unroll
  for (int rr=0;rr<4;rr++){
    Lg[base + rr*RS] = gg[rr];
    La[base + rr*RS] = aa[rr];
  }
}

// ---- node0 matmul, K=2048, A = [x (XN) | h (slot0)] ----
__device__ __forceinline__ void node0_mm(
  const f16* __restrict__ XNH, const f16* __restrict__ XNL,
  const f16* __restrict__ HH, const f16* __restrict__ HL,
  const f16* __restrict__ Wh, const f16* __restrict__ Wl,
  float* __restrict__ Lg, float* __restrict__ La,
  int wid, int q8, int l15, int c0, int wlo)
{
  const int mtile = wid & 3, ks = wid >> 2;
  const int m0 = mtile*16, kk = ks*512, ak = kk & 1023;
  const f16* AHb = (ks<2)? XNH : HH;
  const f16* ALb = (ks<2)? XNL : HL;
  const f16* Ap  = AHb + (m0+l15)*1024 + ak + q8;
  const f16* Alp = ALb + (m0+l15)*1024 + ak + q8;
  const f16* Bg  = Wh + (c0+l15)*2048 + kk + q8;
  const f16* Ba  = Wh + (1024+c0+l15)*2048 + kk + q8;
  f32x4 g0={0,0,0,0},g1={0,0,0,0},a0={0,0,0,0},a1={0,0,0,0};
  if (wlo){
    const f16* Bgl = Wl + (c0+l15)*2048 + kk + q8;
    const f16* Bal = Wl + (1024+c0+l15)*2048 + kk + q8;
    #pragma unroll 2
    for (int s=0;s<512;s+=32){
      half8 ah=ldh8(Ap+s), al=ldh8(Alp+s);
      half8 wg=ldh8(Bg+s), wa=ldh8(Ba+s);
      g0=MFMA(ah,wg,g0); a0=MFMA(ah,wa,a0);
      g1=MFMA(al,wg,g1); a1=MFMA(al,wa,a1);
      g1=MFMA(ah,ldh8(Bgl+s),g1); a1=MFMA(ah,ldh8(Bal+s),a1);
    }
  } else {
    #pragma unroll 2
    for (int s=0;s<512;s+=32){
      half8 ah=ldh8(Ap+s), al=ldh8(Alp+s);
      half8 wg=ldh8(Bg+s), wa=ldh8(Ba+s);
      g0=MFMA(ah,wg,g0); a0=MFMA(ah,wa,a0);
      g1=MFMA(al,wg,g1); a1=MFMA(al,wa,a1);
    }
  }
  f32x4 gg = g0 + g1*RLOSC, aa = a0 + a1*RLOSC;
  const int base = wid*WSZ + (q8>>1)*RS + l15;
  #pragma unroll
  for (int rr=0;rr<4;rr++){
    Lg[base + rr*RS] = gg[rr];
    La[base + rr*RS] = aa[rr];
  }
}

// ---- reduce 4 K-slice partials, apply gate/act -------------------------------
__device__ __forceinline__ float fin_val(const float* __restrict__ Lg, const float* __restrict__ La,
  const float* __restrict__ ST, int sp, int row, int col, int c0, int actk)
{
  const int mtile = row>>4;
  const int e = (row&15)*RS + col;
  float gs=0.f, as=0.f;
  #pragma unroll
  for (int ks=0;ks<4;ks++){
    gs += Lg[(ks*4+mtile)*WSZ + e];
    as += La[(ks*4+mtile)*WSZ + e];
  }
  float spv = ST[sp*65536 + row*1024 + c0 + col];
  return spv + sgm(gs)*(applyact(actk,as)-spv);
}

__device__ __forceinline__ void fin_write(const float* __restrict__ Lg, const float* __restrict__ La,
  float* __restrict__ ST, f16* __restrict__ SH, f16* __restrict__ SL,
  int tid, int c0, int sp, int so, int actk, bool hl)
{
  const int row = tid>>4, col = tid&15;
  float s = fin_val(Lg, La, ST, sp, row, col, c0, actk);
  const int idx = so*65536 + row*1024 + c0 + col;
  ST[idx] = s;
  if (hl){ f16 hi=(f16)s; SH[idx]=hi; SL[idx]=(f16)((s-(float)hi)*LOSC); }
}

// ------------------------------- persistent kernel ------------------------------
__global__ __launch_bounds__(1024,4) void darts_coop(
  const int* __restrict__ X, const float* __restrict__ emb,
  const float* __restrict__ Wout, const float* __restrict__ bout, float* __restrict__ out,
  const f16* __restrict__ W0Th, const f16* __restrict__ W0Tl,
  const f16* __restrict__ WsTh, const f16* __restrict__ WsTl,
  float* __restrict__ ST, f16* __restrict__ SH, f16* __restrict__ SL,
  f16* __restrict__ XNH, f16* __restrict__ XNL,
  unsigned* bar, int wlo)
{
  const int tid = threadIdx.x, b = blockIdx.x;
  const int wid = tid>>6, lane = tid&63, l15 = lane&15, q8 = (lane>>4)*8;
  const int c0 = b*16;                       // this block: all 64 rows, cols c0..c0+15
  __shared__ float Lg[LSZ], La[LSZ];
  unsigned ph = 0;

  for (int t=0; t<TT; ++t){
    // ---- P0: node0: s0 = h + sigmoid(g)*(tanh(a)-h), A=[x|h], K=2048 ----------
    node0_mm(XNH, XNL, SH, SL, W0Th, W0Tl, Lg, La, wid, q8, l15, c0, wlo);
    __syncthreads();
    fin_write(Lg, La, ST, SH, SL, tid, c0, 0, 1, /*tanh*/0, true);
    gbar(bar, ph++);

    // ---- P1: node1 (pred s0, Ws[0], sigmoid); gather x(t+1) (block = batch row b)
    if (t+1 < TT){
      int tok = X[(t+1)*64 + b];
      float v = emb[(size_t)tok*1024 + tid];
      f16 hi=(f16)v;
      XNH[b*1024+tid]=hi; XNL[b*1024+tid]=(f16)((v-(float)hi)*LOSC);
    }
    node_mm(SH+65536, SL+65536, WsTh, WsTl, Lg, La, wid, q8, l15, c0, wlo);
    __syncthreads();
    fin_write(Lg, La, ST, SH, SL, tid, c0, 1, 2, /*sigmoid*/1, true);
    gbar(bar, ph++);

    // ---- P2: nodes 2,3,4 from s1 (relu, relu, identity), sequential -----------
    for (int i=0;i<3;i++){
      if (i) __syncthreads();
      node_mm(SH+2*65536, SL+2*65536,
              WsTh + (size_t)(1+i)*2097152,
              wlo ? WsTl + (size_t)(1+i)*2097152 : (const f16*)0,
              Lg, La, wid, q8, l15, c0, wlo);
      __syncthreads();
      fin_write(Lg, La, ST, SH, SL, tid, c0, 2, 3+i, (i==2)?3:2, i!=2);
    }
    gbar(bar, ph++);

    // ---- P3: node5 (tanh, pred s2=slot3) then node7 (tanh, pred s3=slot4) -----
    node_mm(SH+3*65536, SL+3*65536, WsTh+(size_t)4*2097152,
            wlo? WsTl+(size_t)4*2097152 : (const f16*)0, Lg, La, wid, q8, l15, c0, wlo);
    __syncthreads();
    fin_write(Lg, La, ST, SH, SL, tid, c0, 3, 6, /*tanh*/0, true);
    __syncthreads();
    node_mm(SH+4*65536, SL+4*65536, WsTh+(size_t)6*2097152,
            wlo? WsTl+(size_t)6*2097152 : (const f16*)0, Lg, La, wid, q8, l15, c0, wlo);
    __syncthreads();
    fin_write(Lg, La, ST, SH, SL, tid, c0, 4, 8, /*tanh*/0, false);
    gbar(bar, ph++);

    // ---- P4: node6 (sigmoid) & node8 (relu) from s5 (slot6), mean -> h --------
    node_mm(SH+6*65536, SL+6*65536, WsTh+(size_t)5*2097152,
            wlo? WsTl+(size_t)5*2097152 : (const f16*)0, Lg, La, wid, q8, l15, c0, wlo);
    __syncthreads();
    const int row = tid>>4, col = tid&15;
    float s6v = fin_val(Lg, La, ST, 6, row, col, c0, /*sigmoid*/1);
    __syncthreads();
    node_mm(SH+6*65536, SL+6*65536, WsTh+(size_t)7*2097152,
            wlo? WsTl+(size_t)7*2097152 : (const f16*)0, Lg, La, wid, q8, l15, c0, wlo);
    __syncthreads();
    {
      float s8v = fin_val(Lg, La, ST, 6, row, col, c0, /*relu*/2);
      const int idx = row*1024 + c0 + col;
      float m = (ST[2*65536+idx]+ST[3*65536+idx]+ST[4*65536+idx]+ST[5*65536+idx]
               + ST[6*65536+idx]+ST[8*65536+idx]+s6v+s8v)*0.125f;
      ST[idx]=m;
      f16 hi=(f16)m; SH[idx]=hi; SL[idx]=(f16)((m-(float)hi)*LOSC);
    }
    gbar(bar, ph++);
  }

  // ---- final head: a_hat = h @ Wout + bout ; probs = softmax --------------------
  if (b==0 && tid<256){
    int row = tid>>2, col = tid&3;
    float acc = bout[col];
    const float* hrow = ST + row*1024;
    #pragma unroll 8
    for (int k=0;k<1024;k++) acc += hrow[k]*Wout[k*4+col];
    out[row*4+col] = acc;
    float m = fmaxf(acc, __shfl_xor(acc,1));
    m = fmaxf(m, __shfl_xor(m,2));
    float e = __expf(acc-m);
    float ssum = e + __shfl_xor(e,1);
    ssum = ssum + __shfl_xor(ssum,2);
    out[256 + row*4+col] = e/ssum;
  }
}

// ------------------------------- prep kernels -----------------------------------
__global__ void prep_x0(const int* __restrict__ X, const float* __restrict__ hidden,
  const float* __restrict__ emb, f16* __restrict__ XNH, f16* __restrict__ XNL,
  float* __restrict__ ST, f16* __restrict__ SH, f16* __restrict__ SL, unsigned* bar)
{
  int idx = blockIdx.x*256 + threadIdx.x;   // 65536 threads
  float hv = hidden[idx];
  ST[idx] = hv;
  f16 hh=(f16)hv; SH[idx]=hh; SL[idx]=(f16)((hv-(float)hh)*LOSC);
  int brow = idx>>10, k = idx&1023;
  int tok = X[brow];
  float v = emb[tok*1024+k];
  f16 xh=(f16)v; XNH[idx]=xh; XNL[idx]=(f16)((v-(float)xh)*LOSC);
  if (idx < 1024) bar[idx] = 0u;
}

__global__ void prep_w(const float* __restrict__ W0, const float* __restrict__ Ws,
  f16* __restrict__ W0Th, f16* __restrict__ W0Tl, f16* __restrict__ WsTh, f16* __restrict__ WsTl)
{
  __shared__ float L[64][65];
  int b = blockIdx.x, tid = threadIdx.x;
  const float* src; f16 *Dh, *Dl; int K, tk, tn;
  if (b < 1024){ src=W0; Dh=W0Th; Dl=W0Tl; K=2048; tk=b&31; tn=b>>5; }
  else { int bb=b-1024; int mi=bb>>9; int t2=bb&511; tk=t2&15; tn=t2>>4;
         src = Ws + (size_t)mi*1024*2048; Dh = WsTh + (size_t)mi*2097152;
         Dl = WsTl ? (WsTl + (size_t)mi*2097152) : (f16*)0; K=1024; }
  int k0 = tk*64, n0 = tn*64;
  int rr = tid>>6, cc = tid&63;
  #pragma unroll
  for (int j=0;j<16;j++){
    int r = j*4 + rr;
    L[cc][r] = src[(size_t)(k0+r)*2048 + n0+cc];
  }
  __syncthreads();
  #pragma unroll
  for (int j=0;j<16;j++){
    int n = j*4 + rr;
    float v = L[n][cc];
    f16 hi = (f16)v;
    Dh[(size_t)(n0+n)*K + k0+cc] = hi;
    if (Dl) Dl[(size_t)(n0+n)*K + k0+cc] = (f16)((v-(float)hi)*LOSC);
  }
}

__global__ void sentinel_k(float* __restrict__ out, float v){
  int i = blockIdx.x*256 + threadIdx.x;
  if (i < 512) out[i] = v;
}

// ------------------------------- launcher ----------------------------------------
extern "C" void kernel_launch(void* const* d_in, const int* in_sizes, int n_in,
                              void* d_out, int out_size, void* d_ws, size_t ws_size,
                              hipStream_t stream)
{
  const int*   X      = (const int*)  d_in[0];
  const float* hidden = (const float*)d_in[1];
  const float* emb    = (const float*)d_in[2];
  const float* W0     = (const float*)d_in[3];
  const float* Ws     = (const float*)d_in[4];
  const float* Wout   = (const float*)d_in[5];
  const float* bout   = (const float*)d_in[6];
  float* out = (float*)d_out;

  const size_t SZ_W0   = (size_t)2048*2048*2;      // 8.39 MB (f16)
  const size_t SZ_WS   = (size_t)8*2048*1024*2;    // 33.55 MB
  const size_t SZ_ST   = (size_t)10*65536*4;
  const size_t SZ_SHL  = (size_t)10*65536*2;
  const size_t SZ_XN   = (size_t)65536*2;
  const size_t SZ_BAR  = 4096;

  auto pad = [](size_t x){ return (x + 255) & ~(size_t)255; };
  size_t need_red  = pad(SZ_W0) + pad(SZ_WS) + pad(SZ_ST) + 2*pad(SZ_SHL)
                   + 2*pad(SZ_XN) + pad(SZ_BAR);
  size_t need_full = need_red + pad(SZ_W0) + pad(SZ_WS);

  int wlo;
  if (ws_size >= need_full)      wlo = 1;
  else if (ws_size >= need_red)  wlo = 0;
  else { hipLaunchKernelGGL(sentinel_k, dim3(2), dim3(256), 0, stream, out, 1.0e6f); return; }

  char* w = (char*)d_ws; size_t off = 0;
  auto alloc = [&](size_t bytes)->void*{ void* p = w+off; off += (bytes+255)&~(size_t)255; return p; };
  f16* W0Th = (f16*)alloc(SZ_W0);
  f16* WsTh = (f16*)alloc(SZ_WS);
  f16* W0Tl = wlo ? (f16*)alloc(SZ_W0) : (f16*)0;
  f16* WsTl = wlo ? (f16*)alloc(SZ_WS) : (f16*)0;
  float* ST = (float*)alloc(SZ_ST);
  f16* SH   = (f16*)alloc(SZ_SHL);
  f16* SL   = (f16*)alloc(SZ_SHL);
  f16* XNH  = (f16*)alloc(SZ_XN);
  f16* XNL  = (f16*)alloc(SZ_XN);
  unsigned* bar = (unsigned*)alloc(SZ_BAR);

  hipLaunchKernelGGL(prep_x0, dim3(256), dim3(256), 0, stream,
                     X, hidden, emb, XNH, XNL, ST, SH, SL, bar);
  hipLaunchKernelGGL(prep_w, dim3(5120), dim3(256), 0, stream,
                     W0, Ws, W0Th, W0Tl, WsTh, WsTl);

  // 64 blocks x 1024 threads: one block per batch... per 16-col stripe; 64 CUs,
  // co-residency trivially satisfied (64 << 256 CUs).
  void* args[] = { (void*)&X, (void*)&emb, (void*)&Wout, (void*)&bout, (void*)&out,
                   (void*)&W0Th, (void*)&W0Tl, (void*)&WsTh, (void*)&WsTl,
                   (void*)&ST, (void*)&SH, (void*)&SL, (void*)&XNH, (void*)&XNL,
                   (void*)&bar, (void*)&wlo };
  hipError_t e = hipLaunchCooperativeKernel((void*)darts_coop, dim3(64), dim3(1024), args, 0, stream);
  if (e != hipSuccess){
    hipLaunchKernelGGL(darts_coop, dim3(64), dim3(1024), 0, stream,
                       X, emb, Wout, bout, out, W0Th, W0Tl, WsTh, WsTl,
                       ST, SH, SL, XNH, XNL, bar, wlo);
  }
}

// Round 2
// 64341.949 us; speedup vs baseline: 1.9107x; 1.9107x over previous
//
#include <hip/hip_runtime.h>

#define TT 512

typedef _Float16 f16;
typedef _Float16 half8 __attribute__((ext_vector_type(8)));
typedef float f32x4 __attribute__((ext_vector_type(4)));

#define MFMA(a,b,c) __builtin_amdgcn_mfma_f32_16x16x32_f16((a),(b),(c),0,0,0)
#define LOSC  2048.0f
#define RLOSC 0.00048828125f   // 1/2048

// LDS partial layout: per-wave region of 16 rows, row stride 18 floats.
// (4q+rr)*18 + l15 mod 32 -> max 2-way on the f32 stores (free).
#define RS  18
#define WSZ (16*RS)      // 288 floats per wave region
#define LSZ (16*WSZ)     // 4608 floats per buffer (18.4 KB)

__device__ __forceinline__ half8 ldh8(const f16* p){ return *(const half8*)p; }
__device__ __forceinline__ float sgm(float x){ return 1.f/(1.f+__expf(-x)); }
// act kinds: 0 tanh, 1 sigmoid, 2 relu, 3 identity
__device__ __forceinline__ float applyact(int k, float x){
  if (k==0) return tanhf(x);
  if (k==1) return sgm(x);
  if (k==2) return fmaxf(x,0.f);
  return x;
}

// ---- grid barrier v2: per-block monotonic slot store + all-scan ---------------
// slots at bar[b*4] (16B stride). No RMW, no contention; wave 0 scans 256 slots.
__device__ __forceinline__ void gbar(unsigned* bar, unsigned ph, int b, int wid, int lane){
  __syncthreads();
  const unsigned tgt = ph + 1u;
  if (wid == 0){
    if (lane == 0){
      __builtin_amdgcn_fence(__ATOMIC_RELEASE, "agent");
      __hip_atomic_store(&bar[b*4], tgt, __ATOMIC_RELEASE, __HIP_MEMORY_SCOPE_AGENT);
    }
    for (;;){
      int ok = 1;
      #pragma unroll
      for (int j=0;j<4;j++){
        unsigned v = __hip_atomic_load(&bar[(lane + 64*j)*4], __ATOMIC_RELAXED, __HIP_MEMORY_SCOPE_AGENT);
        ok &= (v >= tgt);
      }
      if (__all(ok)) break;
      __builtin_amdgcn_s_sleep(1);
    }
    if (lane == 0) __builtin_amdgcn_fence(__ATOMIC_ACQUIRE, "agent");
  }
  __syncthreads();
}

// ---- MFMA core: nch chunks of K=32; hi/lo compensated -------------------------
__device__ __forceinline__ void mm_core(
  const f16* __restrict__ Ap, const f16* __restrict__ Alp,
  const f16* __restrict__ Bg, const f16* __restrict__ Ba,
  const f16* __restrict__ Bgl, const f16* __restrict__ Bal,
  int nch, int wlo, float* __restrict__ Lg, float* __restrict__ La,
  int region, int q8, int l15)
{
  f32x4 g0={0,0,0,0},g1={0,0,0,0},a0={0,0,0,0},a1={0,0,0,0};
  #pragma unroll 2
  for (int c=0;c<nch;c++){
    int s = c*32;
    half8 ah=ldh8(Ap+s), al=ldh8(Alp+s);
    half8 wg=ldh8(Bg+s), wa=ldh8(Ba+s);
    g0=MFMA(ah,wg,g0); a0=MFMA(ah,wa,a0);
    g1=MFMA(al,wg,g1); a1=MFMA(al,wa,a1);
    if (wlo){ g1=MFMA(ah,ldh8(Bgl+s),g1); a1=MFMA(ah,ldh8(Bal+s),a1); }
  }
  f32x4 gg = g0 + g1*RLOSC, aa = a0 + a1*RLOSC;
  const int base = region*WSZ + (q8>>1)*RS + l15;   // row-in-tile = q*4+rr
  #pragma unroll
  for (int rr=0;rr<4;rr++){
    Lg[base + rr*RS] = gg[rr];
    La[base + rr*RS] = aa[rr];
  }
}

// ---- standard node (K stride 1024 weights) ------------------------------------
__device__ __forceinline__ void node_std(
  const f16* __restrict__ SHs, const f16* __restrict__ SLs,
  const f16* __restrict__ Wh, const f16* __restrict__ Wl,
  float* __restrict__ Lg, float* __restrict__ La,
  int region, int kk, int nch, int m0, int c0, int q8, int l15, int wlo)
{
  const f16* Ap  = SHs + (m0+l15)*1024 + kk + q8;
  const f16* Alp = SLs + (m0+l15)*1024 + kk + q8;
  const f16* Bg  = Wh + (c0+l15)*1024 + kk + q8;
  const f16* Ba  = Wh + (1024+c0+l15)*1024 + kk + q8;
  const f16* Bgl = wlo ? Wl + (c0+l15)*1024 + kk + q8 : Bg;
  const f16* Bal = wlo ? Wl + (1024+c0+l15)*1024 + kk + q8 : Ba;
  mm_core(Ap,Alp,Bg,Ba,Bgl,Bal,nch,wlo,Lg,La,region,q8,l15);
}

// ---- reduce partials [r0, r0+nr), apply gate/act ------------------------------
__device__ __forceinline__ float fin_val(const float* __restrict__ Lg, const float* __restrict__ La,
  const float* __restrict__ ST, int t256, int m0, int c0, int r0, int nr, int sp, int actk)
{
  const int row = t256>>4, col = t256&15;
  const int e = row*RS + col;
  float gs=0.f, as=0.f;
  for (int r=r0; r<r0+nr; ++r){ gs += Lg[r*WSZ+e]; as += La[r*WSZ+e]; }
  float spv = ST[sp*65536 + (m0+row)*1024 + c0 + col];
  return spv + sgm(gs)*(applyact(actk,as)-spv);
}

__device__ __forceinline__ void fin_write(const float* __restrict__ Lg, const float* __restrict__ La,
  float* __restrict__ ST, f16* __restrict__ SH, f16* __restrict__ SL,
  int t256, int m0, int c0, int r0, int nr, int sp, int so, int actk, bool hl)
{
  float s = fin_val(Lg, La, ST, t256, m0, c0, r0, nr, sp, actk);
  const int row = t256>>4, col = t256&15;
  const int idx = so*65536 + (m0+row)*1024 + c0 + col;
  ST[idx] = s;
  if (hl){ f16 hi=(f16)s; SH[idx]=hi; SL[idx]=(f16)((s-(float)hi)*LOSC); }
}

// ------------------------------- persistent kernel ------------------------------
__global__ __launch_bounds__(1024,4) void darts_coop(
  const int* __restrict__ X, const float* __restrict__ emb,
  const float* __restrict__ Wout, const float* __restrict__ bout, float* __restrict__ out,
  const f16* __restrict__ W0Th, const f16* __restrict__ W0Tl,
  const f16* __restrict__ WsTh, const f16* __restrict__ WsTl,
  float* __restrict__ ST, f16* __restrict__ SH, f16* __restrict__ SL,
  f16* __restrict__ XNH, f16* __restrict__ XNL,
  unsigned* bar, int wlo)
{
  const int tid = threadIdx.x, b = blockIdx.x;
  const int wid = tid>>6, lane = tid&63, l15 = lane&15, q8 = (lane>>4)*8;
  // XCD swizzle: the 4 blocks sharing a weight stripe (same sct) land on one XCD.
  const int mt = (b>>3)&3, sct = (b&7)*8 + (b>>5);
  const int m0 = mt*16, c0 = sct*16;
  __shared__ float Lg[LSZ], La[LSZ];
  __shared__ float S6[256], S8[256];
  unsigned ph = 0;

  for (int t=0; t<TT; ++t){
    // ---- P0: node0 (A=[x|h], K=2048) + x(t+1) gather into alt buffer ----------
    if (t+1 < TT && tid < 256){
      int row = b>>2, col = ((b&3)<<8) + tid;
      int tok = X[(t+1)*64 + row];
      float v = emb[(size_t)tok*1024 + col];
      f16 hi=(f16)v;
      int xi = ((t+1)&1)*65536 + row*1024 + col;
      XNH[xi]=hi; XNL[xi]=(f16)((v-(float)hi)*LOSC);
    }
    {
      const f16* XH = XNH + (t&1)*65536;
      const f16* XL = XNL + (t&1)*65536;
      int kk = wid*128, ak = kk & 1023;
      const f16* Abh = (wid<8)? XH : SH;    // slot0 = h
      const f16* Abl = (wid<8)? XL : SL;
      const f16* Ap  = Abh + (m0+l15)*1024 + ak + q8;
      const f16* Alp = Abl + (m0+l15)*1024 + ak + q8;
      const f16* Bg  = W0Th + (c0+l15)*2048 + kk + q8;
      const f16* Ba  = W0Th + (1024+c0+l15)*2048 + kk + q8;
      const f16* Bgl = wlo ? W0Tl + (c0+l15)*2048 + kk + q8 : Bg;
      const f16* Bal = wlo ? W0Tl + (1024+c0+l15)*2048 + kk + q8 : Ba;
      mm_core(Ap,Alp,Bg,Ba,Bgl,Bal,4,wlo,Lg,La,wid,q8,l15);
    }
    __syncthreads();
    if (tid<256) fin_write(Lg,La,ST,SH,SL, tid, m0,c0, 0,16, /*sp*/0, /*out*/1, /*tanh*/0, true);
    gbar(bar, ph++, b, wid, lane);

    // ---- P1: node1 (pred s0=slot1, Ws[0], sigmoid), 16 waves, K=1024 ----------
    node_std(SH+1*65536, SL+1*65536, WsTh, WsTl, Lg, La, wid, wid*64, 2, m0,c0,q8,l15,wlo);
    __syncthreads();
    if (tid<256) fin_write(Lg,La,ST,SH,SL, tid, m0,c0, 0,16, 1, 2, /*sigmoid*/1, true);
    gbar(bar, ph++, b, wid, lane);

    // ---- P2a: n2 (waves 0-7) || n3 (waves 8-15), both pred s1=slot2, relu -----
    if (wid<8)
      node_std(SH+2*65536, SL+2*65536, WsTh+(size_t)1*2097152,
               wlo? WsTl+(size_t)1*2097152 : (const f16*)0,
               Lg, La, wid, wid*128, 4, m0,c0,q8,l15,wlo);
    else
      node_std(SH+2*65536, SL+2*65536, WsTh+(size_t)2*2097152,
               wlo? WsTl+(size_t)2*2097152 : (const f16*)0,
               Lg, La, wid, (wid-8)*128, 4, m0,c0,q8,l15,wlo);
    __syncthreads();
    if (tid<256)      fin_write(Lg,La,ST,SH,SL, tid,     m0,c0, 0,8, 2, 3, /*relu*/2, true);
    else if (tid<512) fin_write(Lg,La,ST,SH,SL, tid-256, m0,c0, 8,8, 2, 4, /*relu*/2, true);
    __syncthreads();

    // ---- P2b: n4 (identity, pred s1), 16 waves --------------------------------
    node_std(SH+2*65536, SL+2*65536, WsTh+(size_t)3*2097152,
             wlo? WsTl+(size_t)3*2097152 : (const f16*)0,
             Lg, La, wid, wid*64, 2, m0,c0,q8,l15,wlo);
    __syncthreads();
    if (tid<256) fin_write(Lg,La,ST,SH,SL, tid, m0,c0, 0,16, 2, 5, /*identity*/3, false);
    gbar(bar, ph++, b, wid, lane);

    // ---- P3: n5 (pred s2=slot3, tanh) || n7 (pred s3=slot4, tanh) -------------
    if (wid<8)
      node_std(SH+3*65536, SL+3*65536, WsTh+(size_t)4*2097152,
               wlo? WsTl+(size_t)4*2097152 : (const f16*)0,
               Lg, La, wid, wid*128, 4, m0,c0,q8,l15,wlo);
    else
      node_std(SH+4*65536, SL+4*65536, WsTh+(size_t)6*2097152,
               wlo? WsTl+(size_t)6*2097152 : (const f16*)0,
               Lg, La, wid, (wid-8)*128, 4, m0,c0,q8,l15,wlo);
    __syncthreads();
    if (tid<256)      fin_write(Lg,La,ST,SH,SL, tid,     m0,c0, 0,8, 3, 6, /*tanh*/0, true);
    else if (tid<512) fin_write(Lg,La,ST,SH,SL, tid-256, m0,c0, 8,8, 4, 8, /*tanh*/0, false);
    gbar(bar, ph++, b, wid, lane);

    // ---- P4: n6 (sigmoid) || n8 (relu), both pred s5=slot6; mean -> h ---------
    if (wid<8)
      node_std(SH+6*65536, SL+6*65536, WsTh+(size_t)5*2097152,
               wlo? WsTl+(size_t)5*2097152 : (const f16*)0,
               Lg, La, wid, wid*128, 4, m0,c0,q8,l15,wlo);
    else
      node_std(SH+6*65536, SL+6*65536, WsTh+(size_t)7*2097152,
               wlo? WsTl+(size_t)7*2097152 : (const f16*)0,
               Lg, La, wid, (wid-8)*128, 4, m0,c0,q8,l15,wlo);
    __syncthreads();
    if (tid<256)      S6[tid]     = fin_val(Lg,La,ST, tid,     m0,c0, 0,8, 6, /*sigmoid*/1);
    else if (tid<512) S8[tid-256] = fin_val(Lg,La,ST, tid-256, m0,c0, 8,8, 6, /*relu*/2);
    __syncthreads();
    if (tid<256){
      const int row = tid>>4, col = tid&15;
      const int idx = (m0+row)*1024 + c0 + col;
      float m = (ST[2*65536+idx]+ST[3*65536+idx]+ST[4*65536+idx]+ST[5*65536+idx]
               + ST[6*65536+idx]+ST[8*65536+idx]+S6[tid]+S8[tid])*0.125f;
      ST[idx]=m;
      f16 hi=(f16)m; SH[idx]=hi; SL[idx]=(f16)((m-(float)hi)*LOSC);
    }
    gbar(bar, ph++, b, wid, lane);
  }

  // ---- final head: a_hat = h @ Wout + bout ; probs = softmax --------------------
  if (b==0 && tid<256){
    int row = tid>>2, col = tid&3;
    float acc = bout[col];
    const float* hrow = ST + row*1024;
    #pragma unroll 8
    for (int k=0;k<1024;k++) acc += hrow[k]*Wout[k*4+col];
    out[row*4+col] = acc;
    float m = fmaxf(acc, __shfl_xor(acc,1));
    m = fmaxf(m, __shfl_xor(m,2));
    float e = __expf(acc-m);
    float ssum = e + __shfl_xor(e,1);
    ssum = ssum + __shfl_xor(ssum,2);
    out[256 + row*4+col] = e/ssum;
  }
}

// ------------------------------- prep kernels -----------------------------------
__global__ void prep_x0(const int* __restrict__ X, const float* __restrict__ hidden,
  const float* __restrict__ emb, f16* __restrict__ XNH, f16* __restrict__ XNL,
  float* __restrict__ ST, f16* __restrict__ SH, f16* __restrict__ SL, unsigned* bar)
{
  int idx = blockIdx.x*256 + threadIdx.x;   // 65536 threads
  float hv = hidden[idx];
  ST[idx] = hv;
  f16 hh=(f16)hv; SH[idx]=hh; SL[idx]=(f16)((hv-(float)hh)*LOSC);
  int brow = idx>>10, k = idx&1023;
  int tok = X[brow];
  float v = emb[tok*1024+k];
  f16 xh=(f16)v; XNH[idx]=xh; XNL[idx]=(f16)((v-(float)xh)*LOSC);  // slot 0 (t=0)
  if (idx < 4096) bar[idx] = 0u;
}

__global__ void prep_w(const float* __restrict__ W0, const float* __restrict__ Ws,
  f16* __restrict__ W0Th, f16* __restrict__ W0Tl, f16* __restrict__ WsTh, f16* __restrict__ WsTl)
{
  __shared__ float L[64][65];
  int b = blockIdx.x, tid = threadIdx.x;
  const float* src; f16 *Dh, *Dl; int K, tk, tn;
  if (b < 1024){ src=W0; Dh=W0Th; Dl=W0Tl; K=2048; tk=b&31; tn=b>>5; }
  else { int bb=b-1024; int mi=bb>>9; int t2=bb&511; tk=t2&15; tn=t2>>4;
         src = Ws + (size_t)mi*1024*2048; Dh = WsTh + (size_t)mi*2097152;
         Dl = WsTl ? (WsTl + (size_t)mi*2097152) : (f16*)0; K=1024; }
  int k0 = tk*64, n0 = tn*64;
  int rr = tid>>6, cc = tid&63;
  #pragma unroll
  for (int j=0;j<16;j++){
    int r = j*4 + rr;
    L[cc][r] = src[(size_t)(k0+r)*2048 + n0+cc];
  }
  __syncthreads();
  #pragma unroll
  for (int j=0;j<16;j++){
    int n = j*4 + rr;
    float v = L[n][cc];
    f16 hi = (f16)v;
    Dh[(size_t)(n0+n)*K + k0+cc] = hi;
    if (Dl) Dl[(size_t)(n0+n)*K + k0+cc] = (f16)((v-(float)hi)*LOSC);
  }
}

__global__ void sentinel_k(float* __restrict__ out, float v){
  int i = blockIdx.x*256 + threadIdx.x;
  if (i < 512) out[i] = v;
}

// ------------------------------- launcher ----------------------------------------
extern "C" void kernel_launch(void* const* d_in, const int* in_sizes, int n_in,
                              void* d_out, int out_size, void* d_ws, size_t ws_size,
                              hipStream_t stream)
{
  const int*   X      = (const int*)  d_in[0];
  const float* hidden = (const float*)d_in[1];
  const float* emb    = (const float*)d_in[2];
  const float* W0     = (const float*)d_in[3];
  const float* Ws     = (const float*)d_in[4];
  const float* Wout   = (const float*)d_in[5];
  const float* bout   = (const float*)d_in[6];
  float* out = (float*)d_out;

  const size_t SZ_W0   = (size_t)2048*2048*2;      // 8.39 MB (f16)
  const size_t SZ_WS   = (size_t)8*2048*1024*2;    // 33.55 MB
  const size_t SZ_ST   = (size_t)10*65536*4;
  const size_t SZ_SHL  = (size_t)10*65536*2;
  const size_t SZ_XN   = (size_t)2*65536*2;        // double-buffered
  const size_t SZ_BAR  = 16384;

  auto pad = [](size_t x){ return (x + 255) & ~(size_t)255; };
  size_t need_red  = pad(SZ_W0) + pad(SZ_WS) + pad(SZ_ST) + 2*pad(SZ_SHL)
                   + 2*pad(SZ_XN) + pad(SZ_BAR);
  size_t need_full = need_red + pad(SZ_W0) + pad(SZ_WS);

  int wlo;
  if (ws_size >= need_full)      wlo = 1;
  else if (ws_size >= need_red)  wlo = 0;
  else { hipLaunchKernelGGL(sentinel_k, dim3(2), dim3(256), 0, stream, out, 1.0e6f); return; }

  char* w = (char*)d_ws; size_t off = 0;
  auto alloc = [&](size_t bytes)->void*{ void* p = w+off; off += (bytes+255)&~(size_t)255; return p; };
  f16* W0Th = (f16*)alloc(SZ_W0);
  f16* WsTh = (f16*)alloc(SZ_WS);
  f16* W0Tl = wlo ? (f16*)alloc(SZ_W0) : (f16*)0;
  f16* WsTl = wlo ? (f16*)alloc(SZ_WS) : (f16*)0;
  float* ST = (float*)alloc(SZ_ST);
  f16* SH   = (f16*)alloc(SZ_SHL);
  f16* SL   = (f16*)alloc(SZ_SHL);
  f16* XNH  = (f16*)alloc(SZ_XN);
  f16* XNL  = (f16*)alloc(SZ_XN);
  unsigned* bar = (unsigned*)alloc(SZ_BAR);

  hipLaunchKernelGGL(prep_x0, dim3(256), dim3(256), 0, stream,
                     X, hidden, emb, XNH, XNL, ST, SH, SL, bar);
  hipLaunchKernelGGL(prep_w, dim3(5120), dim3(256), 0, stream,
                     W0, Ws, W0Th, W0Tl, WsTh, WsTl);

  // 256 blocks x 1024 threads: 1 block/CU -> co-residency guaranteed.
  void* args[] = { (void*)&X, (void*)&emb, (void*)&Wout, (void*)&bout, (void*)&out,
                   (void*)&W0Th, (void*)&W0Tl, (void*)&WsTh, (void*)&WsTl,
                   (void*)&ST, (void*)&SH, (void*)&SL, (void*)&XNH, (void*)&XNL,
                   (void*)&bar, (void*)&wlo };
  hipError_t e = hipLaunchCooperativeKernel((void*)darts_coop, dim3(256), dim3(1024), args, 0, stream);
  if (e != hipSuccess){
    hipLaunchKernelGGL(darts_coop, dim3(256), dim3(1024), 0, stream,
                       X, emb, Wout, bout, out, W0Th, W0Tl, WsTh, WsTl,
                       ST, SH, SL, XNH, XNL, bar, wlo);
  }
}